// Round 1
// baseline (772.107 us; speedup 1.0000x reference)
//
#include <hip/hip_runtime.h>

#define EPS 1e-5f

constexpr int B   = 64;
constexpr int DIM = 384;
constexpr int PD  = 96;    // PDIM
constexpr int QKD = 16;    // QK
constexpr int N   = 1024;  // H*W
constexpr int OQ  = 128;   // 2*QK + PDIM

// ---------------------------------------------------------------- K1: GN stats
__global__ __launch_bounds__(256) void k_gnstats(const float* __restrict__ x,
                                                 float* __restrict__ stats) {
    int b = blockIdx.x;
    const float4* xp = (const float4*)(x + (size_t)b * DIM * N);
    float s1 = 0.f, s2 = 0.f;
    for (int i = threadIdx.x; i < PD * N / 4; i += 256) {
        float4 v = xp[i];
        s1 += v.x + v.y + v.z + v.w;
        s2 += v.x * v.x + v.y * v.y + v.z * v.z + v.w * v.w;
    }
    __shared__ float r1[4], r2[4];
    for (int o = 32; o > 0; o >>= 1) {
        s1 += __shfl_down(s1, o, 64);
        s2 += __shfl_down(s2, o, 64);
    }
    int wave = threadIdx.x >> 6, lane = threadIdx.x & 63;
    if (lane == 0) { r1[wave] = s1; r2[wave] = s2; }
    __syncthreads();
    if (threadIdx.x == 0) {
        float t1 = r1[0] + r1[1] + r1[2] + r1[3];
        float t2 = r2[0] + r2[1] + r2[2] + r2[3];
        float mu = t1 / (PD * N);
        float var = t2 / (PD * N) - mu * mu;
        stats[b * 2]     = mu;
        stats[b * 2 + 1] = rsqrtf(var + EPS);
    }
}

// ------------------------------------------------- K2: QKV = BN(W @ GN(x1))
// grid (B, 8): 128 output channels x 128 columns per block
__global__ __launch_bounds__(256) void k_qkv(const float* __restrict__ x,
                                             const float* __restrict__ stats,
                                             const float* __restrict__ gnw,
                                             const float* __restrict__ gnb,
                                             const float* __restrict__ W,
                                             const float* __restrict__ bnw,
                                             const float* __restrict__ bnb,
                                             const float* __restrict__ bnm,
                                             const float* __restrict__ bnv,
                                             float* __restrict__ qkv) {
    int b = blockIdx.x, nb = blockIdx.y;
    int tid = threadIdx.x;
    __shared__ float Wl[OQ][33];
    __shared__ float xs[32][132];
    float mu = stats[2 * b], rsig = stats[2 * b + 1];
    int rg = tid >> 4, cg = tid & 15;
    float acc[8][8] = {};
    const float* xb = x + (size_t)b * DIM * N + nb * 128;
    for (int kc = 0; kc < 3; kc++) {
        int k0 = kc * 32;
        #pragma unroll
        for (int ii = 0; ii < 16; ii++) {
            int e = tid + 256 * ii;
            int o = e >> 5, k = e & 31;
            Wl[o][k] = W[o * PD + k0 + k];
        }
        #pragma unroll
        for (int ii = 0; ii < 16; ii++) {
            int e = tid + 256 * ii;
            int kk = e >> 7, j = e & 127;
            int c = k0 + kk;
            float s = rsig * gnw[c];
            float t = gnb[c] - mu * s;
            xs[kk][j] = s * xb[(size_t)c * N + j] + t;
        }
        __syncthreads();
        for (int k = 0; k < 32; k++) {
            float a[8];
            #pragma unroll
            for (int i = 0; i < 8; i++) a[i] = Wl[rg * 8 + i][k];
            float4 b0 = *(const float4*)&xs[k][cg * 8];
            float4 b1 = *(const float4*)&xs[k][cg * 8 + 4];
            float bb[8] = {b0.x, b0.y, b0.z, b0.w, b1.x, b1.y, b1.z, b1.w};
            #pragma unroll
            for (int i = 0; i < 8; i++)
                #pragma unroll
                for (int j = 0; j < 8; j++) acc[i][j] += a[i] * bb[j];
        }
        __syncthreads();
    }
    #pragma unroll
    for (int i = 0; i < 8; i++) {
        int o = rg * 8 + i;
        float inv  = bnw[o] * rsqrtf(bnv[o] + EPS);
        float bias = bnb[o] - bnm[o] * inv;
        float* op = qkv + ((size_t)b * OQ + o) * N + nb * 128 + cg * 8;
        #pragma unroll
        for (int j = 0; j < 8; j++) op[j] = acc[i][j] * inv + bias;
    }
}

// ---------------------------------------- K3: flash attention, 64q x 64k tiles
// grid (B, 16). 256 threads: PV as 8 ch-groups x 32 (query jj, jj+32)
__global__ __launch_bounds__(256) void k_attn(const float* __restrict__ qkv,
                                              float* __restrict__ x1o) {
    int b = blockIdx.x, qb = blockIdx.y;
    int tid = threadIdx.x;
    __shared__ float qs[QKD][64];
    __shared__ float ks[QKD][64];
    __shared__ float vs[PD][64];
    __shared__ float S[64][65];
    __shared__ float mst[64], lst[64], crw[64];
    const float* qk = qkv + (size_t)b * OQ * N;
    int n0 = qb * 64;
    #pragma unroll
    for (int it = 0; it < 4; it++) {
        int e = tid + 256 * it;
        int c = e >> 6, j = e & 63;
        qs[c][j] = qk[c * N + n0 + j];
    }
    if (tid < 64) { mst[tid] = -1e30f; lst[tid] = 0.f; }
    int cg = tid >> 5;   // 8 groups of 12 channels
    int jj = tid & 31;   // queries jj, jj+32
    float acc[12][2] = {};
    int sj  = tid >> 2;        // scoring: query
    int sm0 = (tid & 3) * 16;  // scoring: key range
    __syncthreads();
    for (int mc = 0; mc < 16; mc++) {
        int m0 = mc * 64;
        #pragma unroll
        for (int it = 0; it < 4; it++) {
            int e = tid + 256 * it;
            int c = e >> 6, m = e & 63;
            ks[c][m] = qk[(QKD + c) * N + m0 + m];
        }
        #pragma unroll
        for (int it = 0; it < 24; it++) {
            int e = tid + 256 * it;
            int c = e >> 6, m = e & 63;
            vs[c][m] = qk[(2 * QKD + c) * N + m0 + m];
        }
        __syncthreads();
        {   // scores: 16 keys per thread for query sj
            float sacc[16] = {};
            #pragma unroll
            for (int c = 0; c < QKD; c++) {
                float qv = qs[c][sj];
                #pragma unroll
                for (int m = 0; m < 16; m++) sacc[m] += qv * ks[c][sm0 + m];
            }
            #pragma unroll
            for (int m = 0; m < 16; m++) S[sj][sm0 + m] = sacc[m] * 0.25f;
        }
        __syncthreads();
        if (tid < 64) {  // per-query running max update
            int j = tid;
            float cmax = -1e30f;
            for (int m = 0; m < 64; m++) cmax = fmaxf(cmax, S[j][m]);
            float newm = fmaxf(mst[j], cmax);
            float corr = __expf(mst[j] - newm);
            crw[j] = corr;
            mst[j] = newm;
            lst[j] *= corr;
        }
        __syncthreads();
        {   // rescale accumulators
            float c0 = crw[jj], c1 = crw[jj + 32];
            #pragma unroll
            for (int ci = 0; ci < 12; ci++) { acc[ci][0] *= c0; acc[ci][1] *= c1; }
        }
        // exponentiate + row sums (wave handles one row per iter; m = lane)
        #pragma unroll
        for (int it = 0; it < 16; it++) {
            int idx = tid + 256 * it;
            int m = idx & 63, j = idx >> 6;
            float p = __expf(S[j][m] - mst[j]);
            S[j][m] = p;
            float ssum = p;
            for (int o = 32; o > 0; o >>= 1) ssum += __shfl_down(ssum, o, 64);
            if ((tid & 63) == 0) lst[j] += ssum;
        }
        __syncthreads();
        // PV accumulate
        for (int mg = 0; mg < 16; mg++) {
            int m = mg * 4;
            float p0a = S[jj][m],      p1a = S[jj][m + 1];
            float p2a = S[jj][m + 2],  p3a = S[jj][m + 3];
            float p0b = S[jj + 32][m],     p1b = S[jj + 32][m + 1];
            float p2b = S[jj + 32][m + 2], p3b = S[jj + 32][m + 3];
            #pragma unroll
            for (int ci = 0; ci < 12; ci++) {
                int c = cg * 12 + ci;
                float4 v4 = *(const float4*)&vs[c][m];
                acc[ci][0] += p0a * v4.x + p1a * v4.y + p2a * v4.z + p3a * v4.w;
                acc[ci][1] += p0b * v4.x + p1b * v4.y + p2b * v4.z + p3b * v4.w;
            }
        }
        __syncthreads();
    }
    #pragma unroll
    for (int ci = 0; ci < 12; ci++) {
        int c = cg * 12 + ci;
        float* op = x1o + ((size_t)b * PD + c) * N + n0;
        op[jj]      = acc[ci][0] / lst[jj];
        op[jj + 32] = acc[ci][1] / lst[jj + 32];
    }
}

// --------------------------- K4: out = BN(P @ silu(concat(x1o, x2)))
// grid (B, 3, 8): 128 rows x 128 cols per block, K = 384
__global__ __launch_bounds__(256) void k_proj(const float* __restrict__ x,
                                              const float* __restrict__ x1o,
                                              const float* __restrict__ W,
                                              const float* __restrict__ bnw,
                                              const float* __restrict__ bnb,
                                              const float* __restrict__ bnm,
                                              const float* __restrict__ bnv,
                                              float* __restrict__ out) {
    int b = blockIdx.x, rb = blockIdx.y, nb = blockIdx.z;
    int tid = threadIdx.x;
    __shared__ float Pl[128][33];
    __shared__ float ysl[32][132];
    int rg = tid >> 4, cg = tid & 15;
    float acc[8][8] = {};
    const float* xb = x   + (size_t)b * DIM * N + nb * 128;
    const float* ob = x1o + (size_t)b * PD  * N + nb * 128;
    for (int kc = 0; kc < 12; kc++) {
        int k0 = kc * 32;
        #pragma unroll
        for (int ii = 0; ii < 16; ii++) {
            int e = tid + 256 * ii;
            int o = e >> 5, k = e & 31;
            Pl[o][k] = W[(rb * 128 + o) * DIM + k0 + k];
        }
        #pragma unroll
        for (int ii = 0; ii < 16; ii++) {
            int e = tid + 256 * ii;
            int kk = e >> 7, j = e & 127;
            int c = k0 + kk;
            float v = (c < PD) ? ob[(size_t)c * N + j] : xb[(size_t)c * N + j];
            ysl[kk][j] = v / (1.f + __expf(-v));
        }
        __syncthreads();
        for (int k = 0; k < 32; k++) {
            float a[8];
            #pragma unroll
            for (int i = 0; i < 8; i++) a[i] = Pl[rg * 8 + i][k];
            float4 b0 = *(const float4*)&ysl[k][cg * 8];
            float4 b1 = *(const float4*)&ysl[k][cg * 8 + 4];
            float bb[8] = {b0.x, b0.y, b0.z, b0.w, b1.x, b1.y, b1.z, b1.w};
            #pragma unroll
            for (int i = 0; i < 8; i++)
                #pragma unroll
                for (int j = 0; j < 8; j++) acc[i][j] += a[i] * bb[j];
        }
        __syncthreads();
    }
    #pragma unroll
    for (int i = 0; i < 8; i++) {
        int o = rb * 128 + rg * 8 + i;
        float inv  = bnw[o] * rsqrtf(bnv[o] + EPS);
        float bias = bnb[o] - bnm[o] * inv;
        float* op = out + ((size_t)b * DIM + o) * N + nb * 128 + cg * 8;
        #pragma unroll
        for (int j = 0; j < 8; j++) op[j] = acc[i][j] * inv + bias;
    }
}

// -----------------------------------------------------------------------------
extern "C" void kernel_launch(void* const* d_in, const int* in_sizes, int n_in,
                              void* d_out, int out_size, void* d_ws, size_t ws_size,
                              hipStream_t stream) {
    const float* x    = (const float*)d_in[0];
    const float* gnw  = (const float*)d_in[1];
    const float* gnb  = (const float*)d_in[2];
    const float* qkvw = (const float*)d_in[3];
    const float* qbnw = (const float*)d_in[4];
    const float* qbnb = (const float*)d_in[5];
    const float* qbnm = (const float*)d_in[6];
    const float* qbnv = (const float*)d_in[7];
    const float* pw   = (const float*)d_in[8];
    const float* pbnw = (const float*)d_in[9];
    const float* pbnb = (const float*)d_in[10];
    const float* pbnm = (const float*)d_in[11];
    const float* pbnv = (const float*)d_in[12];
    float* out = (float*)d_out;

    char* ws = (char*)d_ws;
    float* stats = (float*)ws;                                   // B*2
    float* qkv   = (float*)(ws + 1024);                          // B*OQ*N
    float* x1o   = (float*)(ws + 1024 + (size_t)B * OQ * N * 4); // B*PD*N

    k_gnstats<<<B, 256, 0, stream>>>(x, stats);
    k_qkv<<<dim3(B, 8), 256, 0, stream>>>(x, stats, gnw, gnb, qkvw,
                                          qbnw, qbnb, qbnm, qbnv, qkv);
    k_attn<<<dim3(B, 16), 256, 0, stream>>>(qkv, x1o);
    k_proj<<<dim3(B, 3, 8), 256, 0, stream>>>(x, x1o, pw,
                                              pbnw, pbnb, pbnm, pbnv, out);
}

// Round 3
// 259.187 us; speedup vs baseline: 2.9790x; 2.9790x over previous
//
#include <hip/hip_runtime.h>

#define EPS 1e-5f

constexpr int B   = 64;
constexpr int DIM = 384;
constexpr int PD  = 96;    // PDIM
constexpr int QKD = 16;    // QK
constexpr int N   = 1024;  // H*W
constexpr int OQ  = 128;   // 2*QK + PDIM
constexpr int Y2C = DIM - PD;  // 288

typedef __attribute__((ext_vector_type(8))) short bf16x8;
typedef __attribute__((ext_vector_type(16))) float f32x16;

#define MFMA(a, b, c) __builtin_amdgcn_mfma_f32_32x32x16_bf16((a), (b), (c), 0, 0, 0)

__device__ __forceinline__ unsigned short f2bf(float f) {
    union { float f; unsigned u; } v; v.f = f;
    unsigned r = v.u + 0x7fffu + ((v.u >> 16) & 1u);
    return (unsigned short)(r >> 16);
}
__device__ __forceinline__ unsigned pack2(float a, float b) {
    return (unsigned)f2bf(a) | ((unsigned)f2bf(b) << 16);
}
__device__ __forceinline__ f32x16 zero16() {
    f32x16 z;
#pragma unroll
    for (int i = 0; i < 16; i++) z[i] = 0.f;
    return z;
}

// ---------------------------------------------------------------- K1: GN stats
__global__ __launch_bounds__(256) void k_gnstats(const float* __restrict__ x,
                                                 float* __restrict__ stats) {
    int b = blockIdx.x;
    const float4* xp = (const float4*)(x + (size_t)b * DIM * N);
    float s1 = 0.f, s2 = 0.f;
    for (int i = threadIdx.x; i < PD * N / 4; i += 256) {
        float4 v = xp[i];
        s1 += v.x + v.y + v.z + v.w;
        s2 += v.x * v.x + v.y * v.y + v.z * v.z + v.w * v.w;
    }
    __shared__ float r1[4], r2[4];
    for (int o = 32; o > 0; o >>= 1) {
        s1 += __shfl_down(s1, o, 64);
        s2 += __shfl_down(s2, o, 64);
    }
    int wave = threadIdx.x >> 6, lane = threadIdx.x & 63;
    if (lane == 0) { r1[wave] = s1; r2[wave] = s2; }
    __syncthreads();
    if (threadIdx.x == 0) {
        float t1 = r1[0] + r1[1] + r1[2] + r1[3];
        float t2 = r2[0] + r2[1] + r2[2] + r2[3];
        float mu = t1 / (PD * N);
        float var = t2 / (PD * N) - mu * mu;
        stats[b * 2]     = mu;
        stats[b * 2 + 1] = rsqrtf(var + EPS);
    }
}

// ---------------------- K2: QKV = BN(W @ GN(x1)); emit Qt/Kt transposed bf16, V bf16
__global__ __launch_bounds__(256) void k_qkv(const float* __restrict__ x,
                                             const float* __restrict__ stats,
                                             const float* __restrict__ gnw,
                                             const float* __restrict__ gnb,
                                             const float* __restrict__ W,
                                             const float* __restrict__ bnw,
                                             const float* __restrict__ bnb,
                                             const float* __restrict__ bnm,
                                             const float* __restrict__ bnv,
                                             short* __restrict__ Qt,
                                             short* __restrict__ Kt,
                                             short* __restrict__ Vw) {
    int b = blockIdx.x, nb = blockIdx.y;
    int tid = threadIdx.x;
    __shared__ float Wl[OQ][33];
    __shared__ float xs[32][132];
    float mu = stats[2 * b], rsig = stats[2 * b + 1];
    int rg = tid >> 4, cg = tid & 15;
    float acc[8][8] = {};
    const float* xb = x + (size_t)b * DIM * N + nb * 128;
    for (int kc = 0; kc < 3; kc++) {
        int k0 = kc * 32;
        #pragma unroll
        for (int ii = 0; ii < 16; ii++) {
            int e = tid + 256 * ii;
            int o = e >> 5, k = e & 31;
            Wl[o][k] = W[o * PD + k0 + k];
        }
        #pragma unroll
        for (int ii = 0; ii < 16; ii++) {
            int e = tid + 256 * ii;
            int kk = e >> 7, j = e & 127;
            int c = k0 + kk;
            float s = rsig * gnw[c];
            float t = gnb[c] - mu * s;
            xs[kk][j] = s * xb[(size_t)c * N + j] + t;
        }
        __syncthreads();
        for (int k = 0; k < 32; k++) {
            float a[8];
            #pragma unroll
            for (int i = 0; i < 8; i++) a[i] = Wl[rg * 8 + i][k];
            float4 b0 = *(const float4*)&xs[k][cg * 8];
            float4 b1 = *(const float4*)&xs[k][cg * 8 + 4];
            float bb[8] = {b0.x, b0.y, b0.z, b0.w, b1.x, b1.y, b1.z, b1.w};
            #pragma unroll
            for (int i = 0; i < 8; i++)
                #pragma unroll
                for (int j = 0; j < 8; j++) acc[i][j] += a[i] * bb[j];
        }
        __syncthreads();
    }
    int nbase = nb * 128 + cg * 8;
    #pragma unroll
    for (int i = 0; i < 8; i++) {
        int o = rg * 8 + i;
        float inv  = bnw[o] * rsqrtf(bnv[o] + EPS);
        float bias = bnb[o] - bnm[o] * inv;
        float val[8];
        #pragma unroll
        for (int j = 0; j < 8; j++) val[j] = acc[i][j] * inv + bias;
        if (o < QKD) {
            #pragma unroll
            for (int j = 0; j < 8; j++)
                Qt[((size_t)b * N + nbase + j) * QKD + o] = (short)f2bf(val[j]);
        } else if (o < 2 * QKD) {
            #pragma unroll
            for (int j = 0; j < 8; j++)
                Kt[((size_t)b * N + nbase + j) * QKD + (o - QKD)] = (short)f2bf(val[j]);
        } else {
            short* vp = Vw + ((size_t)b * PD + (o - 2 * QKD)) * N + nbase;
            #pragma unroll
            for (int j = 0; j < 8; j += 2)
                *(unsigned*)(vp + j) = pack2(val[j], val[j + 1]);
        }
    }
}

// ---------------------------------------- K3: MFMA flash attention
// grid (B, 8): 4 waves/block, each wave owns 32 queries; full 1024-key loop.
// Writes silu(out) transposed bf16 into y1t[b][n][96].
__global__ __launch_bounds__(256) void k_attn(const short* __restrict__ Qt,
                                              const short* __restrict__ Kt,
                                              const short* __restrict__ Vb,
                                              short* __restrict__ y1t) {
    int b = blockIdx.x;
    int w = threadIdx.x >> 6, lane = threadIdx.x & 63;
    int col = lane & 31, hi = lane >> 5;
    int q0 = blockIdx.y * 128 + w * 32;

    const bf16x8 qf = *(const bf16x8*)(Qt + ((size_t)b * N + q0 + col) * QKD + hi * 8);
    f32x16 acc0 = zero16(), acc1 = zero16(), acc2 = zero16();
    float m = -1e30f, lsum = 0.f;
    const short* kbase = Kt + (size_t)b * N * QKD;
    const short* vbase = Vb + (size_t)b * PD * N;

    for (int m0 = 0; m0 < N; m0 += 32) {
        bf16x8 kf = *(const bf16x8*)(kbase + (size_t)(m0 + col) * QKD + hi * 8);
        f32x16 s = MFMA(kf, qf, zero16());   // s[r] = S[key=m0+crow(r,hi)][q]
        float cm = -1e30f;
        #pragma unroll
        for (int r = 0; r < 16; r++) { s[r] *= 0.25f; cm = fmaxf(cm, s[r]); }
        cm = fmaxf(cm, __shfl_xor(cm, 32, 64));
        float mnew = fmaxf(m, cm);
        float corr = __expf(m - mnew);
        m = mnew;
        lsum *= corr;
        #pragma unroll
        for (int r = 0; r < 16; r++) { acc0[r] *= corr; acc1[r] *= corr; acc2[r] *= corr; }
        float ps = 0.f;
        unsigned pw[8];
        #pragma unroll
        for (int j = 0; j < 8; j++) {
            float p0 = __expf(s[2 * j] - m), p1 = __expf(s[2 * j + 1] - m);
            ps += p0 + p1;
            pw[j] = pack2(p0, p1);
        }
        ps += __shfl_xor(ps, 32, 64);
        lsum += ps;
        unsigned xw[8];
        #pragma unroll
        for (int j = 0; j < 8; j++) xw[j] = __shfl_xor(pw[j], 32, 64);
        // Assemble B-fragments: P[k][q] with k = ks*16 + hi*8 + j (contiguous-8 layout)
        union { unsigned u[4]; bf16x8 v; } pb0, pb1;
        if (hi == 0) {
            pb0.u[0] = pw[0]; pb0.u[1] = pw[1]; pb0.u[2] = xw[0]; pb0.u[3] = xw[1];
            pb1.u[0] = pw[4]; pb1.u[1] = pw[5]; pb1.u[2] = xw[4]; pb1.u[3] = xw[5];
        } else {
            pb0.u[0] = xw[2]; pb0.u[1] = xw[3]; pb0.u[2] = pw[2]; pb0.u[3] = pw[3];
            pb1.u[0] = xw[6]; pb1.u[1] = xw[7]; pb1.u[2] = pw[6]; pb1.u[3] = pw[7];
        }
        const short* vrow = vbase + (size_t)col * N + m0 + hi * 8;
        bf16x8 v00 = *(const bf16x8*)(vrow);
        bf16x8 v01 = *(const bf16x8*)(vrow + 16);
        acc0 = MFMA(v00, pb0.v, acc0);
        acc0 = MFMA(v01, pb1.v, acc0);
        const short* vrow1 = vrow + 32 * N;
        bf16x8 v10 = *(const bf16x8*)(vrow1);
        bf16x8 v11 = *(const bf16x8*)(vrow1 + 16);
        acc1 = MFMA(v10, pb0.v, acc1);
        acc1 = MFMA(v11, pb1.v, acc1);
        const short* vrow2 = vrow1 + 32 * N;
        bf16x8 v20 = *(const bf16x8*)(vrow2);
        bf16x8 v21 = *(const bf16x8*)(vrow2 + 16);
        acc2 = MFMA(v20, pb0.v, acc2);
        acc2 = MFMA(v21, pb1.v, acc2);
    }
    float inv = 1.f / lsum;
    short* yrow = y1t + ((size_t)b * N + q0 + col) * PD;
    #pragma unroll
    for (int cg = 0; cg < 3; cg++) {
        f32x16 a = (cg == 0) ? acc0 : ((cg == 1) ? acc1 : acc2);
        #pragma unroll
        for (int j = 0; j < 8; j++) {
            float v0 = a[2 * j] * inv, v1 = a[2 * j + 1] * inv;
            v0 = v0 / (1.f + __expf(-v0));   // silu
            v1 = v1 / (1.f + __expf(-v1));
            int c = cg * 32 + ((2 * j) & 3) + 8 * (j >> 1) + 4 * hi;
            *(unsigned*)(yrow + c) = pack2(v0, v1);
        }
    }
}

// ---------------- K4: y2t[b][n][c-96] = bf16(silu(x[b][c][n])) for c in [96,384)
__global__ __launch_bounds__(256) void k_trans(const float* __restrict__ x,
                                               short* __restrict__ y2t) {
    int b = blockIdx.x, ct = blockIdx.y, nt = blockIdx.z;
    int tid = threadIdx.x;
    __shared__ short t[32][130];
    int c0 = PD + ct * 32, n0 = nt * 128;
    const float* xb = x + ((size_t)b * DIM + c0) * N + n0;
    #pragma unroll
    for (int i = 0; i < 16; i++) {
        int e = tid + 256 * i;
        int c = e >> 7, n = e & 127;
        float v = xb[(size_t)c * N + n];
        t[c][n] = (short)f2bf(v / (1.f + __expf(-v)));
    }
    __syncthreads();
    #pragma unroll
    for (int i = 0; i < 8; i++) {
        int e = tid + 256 * i;
        int n = e >> 4, cp = e & 15;
        unsigned lo = (unsigned short)t[2 * cp][n];
        unsigned hi = (unsigned short)t[2 * cp + 1][n];
        *(unsigned*)(y2t + ((size_t)b * N + n0 + n) * Y2C + ct * 32 + 2 * cp) = lo | (hi << 16);
    }
}

// ---------------- K5: W' = bf16(proj_w * bn_inv), bias[o]
__global__ __launch_bounds__(256) void k_wconv(const float* __restrict__ W,
                                               const float* __restrict__ bnw,
                                               const float* __restrict__ bnb,
                                               const float* __restrict__ bnm,
                                               const float* __restrict__ bnv,
                                               short* __restrict__ Wp,
                                               float* __restrict__ bias) {
    int idx = blockIdx.x * 256 + threadIdx.x;
    int o = idx / DIM;
    float inv = bnw[o] * rsqrtf(bnv[o] + EPS);
    Wp[idx] = (short)f2bf(W[idx] * inv);
    if (idx < DIM) bias[idx] = bnb[idx] - bnm[idx] * (bnw[idx] * rsqrtf(bnv[idx] + EPS));
}

// ---------------- K6: out = W' @ [y1t; y2t] + bias  (MFMA, 32x32 tile per wave)
// grid (B, 6, 16): block covers 64 o x 64 n with 4 waves.
__global__ __launch_bounds__(256) void k_proj(const short* __restrict__ Wp,
                                              const short* __restrict__ y1t,
                                              const short* __restrict__ y2t,
                                              const float* __restrict__ bias,
                                              float* __restrict__ out) {
    int b = blockIdx.x;
    int w = threadIdx.x >> 6, lane = threadIdx.x & 63;
    int col = lane & 31, hi = lane >> 5;
    int o0 = blockIdx.y * 64 + (w >> 1) * 32;
    int n0 = blockIdx.z * 64 + (w & 1) * 32;
    const short* wrow  = Wp  + (size_t)(o0 + col) * DIM + hi * 8;
    const short* yrow1 = y1t + ((size_t)b * N + n0 + col) * PD  + hi * 8;
    const short* yrow2 = y2t + ((size_t)b * N + n0 + col) * Y2C + hi * 8;
    f32x16 acc = zero16();
    #pragma unroll 3
    for (int k0 = 0; k0 < PD; k0 += 16) {
        bf16x8 af = *(const bf16x8*)(wrow + k0);
        bf16x8 bf = *(const bf16x8*)(yrow1 + k0);
        acc = MFMA(af, bf, acc);
    }
    #pragma unroll 6
    for (int k0 = 0; k0 < Y2C; k0 += 16) {
        bf16x8 af = *(const bf16x8*)(wrow + PD + k0);
        bf16x8 bf = *(const bf16x8*)(yrow2 + k0);
        acc = MFMA(af, bf, acc);
    }
    #pragma unroll
    for (int r = 0; r < 16; r++) {
        int o = o0 + (r & 3) + 8 * (r >> 2) + 4 * hi;
        out[((size_t)b * DIM + o) * N + n0 + col] = acc[r] + bias[o];
    }
}

// -----------------------------------------------------------------------------
// ws layout (total ~50.6 MB, fits the proven-safe 58.7 MB budget from R0):
//   [stats 1K | Wp 288K | bias 1.5K | y1t 12.6M | Qt 2M | Kt 2M | Vw 12.6M ...]
//   y2t (37.75M) aliases [Qt,Kt,Vw] + 21M tail — Qt/Kt/Vw are dead once k_attn
//   completes, k_trans runs after k_attn on the same stream, and every buffer
//   is rewritten each call (replay-safe).
extern "C" void kernel_launch(void* const* d_in, const int* in_sizes, int n_in,
                              void* d_out, int out_size, void* d_ws, size_t ws_size,
                              hipStream_t stream) {
    const float* x    = (const float*)d_in[0];
    const float* gnw  = (const float*)d_in[1];
    const float* gnb  = (const float*)d_in[2];
    const float* qkvw = (const float*)d_in[3];
    const float* qbnw = (const float*)d_in[4];
    const float* qbnb = (const float*)d_in[5];
    const float* qbnm = (const float*)d_in[6];
    const float* qbnv = (const float*)d_in[7];
    const float* pw   = (const float*)d_in[8];
    const float* pbnw = (const float*)d_in[9];
    const float* pbnb = (const float*)d_in[10];
    const float* pbnm = (const float*)d_in[11];
    const float* pbnv = (const float*)d_in[12];
    float* out = (float*)d_out;

    char* p = (char*)d_ws;
    float* stats = (float*)p;  p += 1024;
    short* Wp    = (short*)p;  p += (size_t)DIM * DIM * 2;     // 288 KB
    float* bias  = (float*)p;  p += 1536;                      // DIM*4
    short* y1t   = (short*)p;  p += (size_t)B * N * PD * 2;    // 12.6 MB
    short* Qt    = (short*)p;                                  // 2 MB   (dead after k_attn)
    short* Kt    = Qt + (size_t)B * N * QKD;                   // 2 MB   (dead after k_attn)
    short* Vw    = Kt + (size_t)B * N * QKD;                   // 12.6 MB(dead after k_attn)
    short* y2t   = Qt;                                         // 37.75 MB, aliases Qt/Kt/Vw+tail

    k_gnstats<<<B, 256, 0, stream>>>(x, stats);
    k_wconv<<<DIM * DIM / 256, 256, 0, stream>>>(pw, pbnw, pbnb, pbnm, pbnv, Wp, bias);
    k_qkv<<<dim3(B, 8), 256, 0, stream>>>(x, stats, gnw, gnb, qkvw,
                                          qbnw, qbnb, qbnm, qbnv, Qt, Kt, Vw);
    k_attn<<<dim3(B, 8), 256, 0, stream>>>(Qt, Kt, Vw, y1t);
    k_trans<<<dim3(B, 9, 8), 256, 0, stream>>>(x, y2t);
    k_proj<<<dim3(B, 6, 16), 256, 0, stream>>>(Wp, y1t, y2t, bias, out);
}

// Round 4
// 187.937 us; speedup vs baseline: 4.1083x; 1.3791x over previous
//
#include <hip/hip_runtime.h>

#define EPS 1e-5f

constexpr int B   = 64;
constexpr int DIM = 384;
constexpr int PD  = 96;    // PDIM
constexpr int QKD = 16;    // QK
constexpr int N   = 1024;  // H*W
constexpr int OQ  = 128;   // 2*QK + PDIM
constexpr int Y2C = DIM - PD;  // 288

typedef __attribute__((ext_vector_type(8))) short bf16x8;
typedef __attribute__((ext_vector_type(16))) float f32x16;

#define MFMA(a, b, c) __builtin_amdgcn_mfma_f32_32x32x16_bf16((a), (b), (c), 0, 0, 0)

// async global->LDS, 16B per lane; LDS dest is wave-uniform base + lane*16
#define GLOAD16(gsrc, ldst)                                                    \
    __builtin_amdgcn_global_load_lds(                                          \
        (const __attribute__((address_space(1))) void*)(gsrc),                 \
        (__attribute__((address_space(3))) void*)(ldst), 16, 0, 0)

__device__ __forceinline__ unsigned short f2bf(float f) {
    union { float f; unsigned u; } v; v.f = f;
    unsigned r = v.u + 0x7fffu + ((v.u >> 16) & 1u);
    return (unsigned short)(r >> 16);
}
__device__ __forceinline__ unsigned pack2(float a, float b) {
    return (unsigned)f2bf(a) | ((unsigned)f2bf(b) << 16);
}
__device__ __forceinline__ f32x16 zero16() {
    f32x16 z;
#pragma unroll
    for (int i = 0; i < 16; i++) z[i] = 0.f;
    return z;
}

// ---------------------------------------------------------------- K1: GN stats
__global__ __launch_bounds__(256) void k_gnstats(const float* __restrict__ x,
                                                 float* __restrict__ stats) {
    int b = blockIdx.x;
    const float4* xp = (const float4*)(x + (size_t)b * DIM * N);
    float s1 = 0.f, s2 = 0.f;
    for (int i = threadIdx.x; i < PD * N / 4; i += 256) {
        float4 v = xp[i];
        s1 += v.x + v.y + v.z + v.w;
        s2 += v.x * v.x + v.y * v.y + v.z * v.z + v.w * v.w;
    }
    __shared__ float r1[4], r2[4];
    for (int o = 32; o > 0; o >>= 1) {
        s1 += __shfl_down(s1, o, 64);
        s2 += __shfl_down(s2, o, 64);
    }
    int wave = threadIdx.x >> 6, lane = threadIdx.x & 63;
    if (lane == 0) { r1[wave] = s1; r2[wave] = s2; }
    __syncthreads();
    if (threadIdx.x == 0) {
        float t1 = r1[0] + r1[1] + r1[2] + r1[3];
        float t2 = r2[0] + r2[1] + r2[2] + r2[3];
        float mu = t1 / (PD * N);
        float var = t2 / (PD * N) - mu * mu;
        stats[b * 2]     = mu;
        stats[b * 2 + 1] = rsqrtf(var + EPS);
    }
}

// ---------------------- K2: QKV = BN(W @ GN(x1)); emit Qt/Kt transposed bf16, V bf16
__global__ __launch_bounds__(256) void k_qkv(const float* __restrict__ x,
                                             const float* __restrict__ stats,
                                             const float* __restrict__ gnw,
                                             const float* __restrict__ gnb,
                                             const float* __restrict__ W,
                                             const float* __restrict__ bnw,
                                             const float* __restrict__ bnb,
                                             const float* __restrict__ bnm,
                                             const float* __restrict__ bnv,
                                             short* __restrict__ Qt,
                                             short* __restrict__ Kt,
                                             short* __restrict__ Vw) {
    int b = blockIdx.x, nb = blockIdx.y;
    int tid = threadIdx.x;
    __shared__ float Wl[OQ][33];
    __shared__ float xs[32][132];
    float mu = stats[2 * b], rsig = stats[2 * b + 1];
    int rg = tid >> 4, cg = tid & 15;
    float acc[8][8] = {};
    const float* xb = x + (size_t)b * DIM * N + nb * 128;
    for (int kc = 0; kc < 3; kc++) {
        int k0 = kc * 32;
        #pragma unroll
        for (int ii = 0; ii < 16; ii++) {
            int e = tid + 256 * ii;
            int o = e >> 5, k = e & 31;
            Wl[o][k] = W[o * PD + k0 + k];
        }
        #pragma unroll
        for (int ii = 0; ii < 16; ii++) {
            int e = tid + 256 * ii;
            int kk = e >> 7, j = e & 127;
            int c = k0 + kk;
            float s = rsig * gnw[c];
            float t = gnb[c] - mu * s;
            xs[kk][j] = s * xb[(size_t)c * N + j] + t;
        }
        __syncthreads();
        for (int k = 0; k < 32; k++) {
            float a[8];
            #pragma unroll
            for (int i = 0; i < 8; i++) a[i] = Wl[rg * 8 + i][k];
            float4 b0 = *(const float4*)&xs[k][cg * 8];
            float4 b1 = *(const float4*)&xs[k][cg * 8 + 4];
            float bb[8] = {b0.x, b0.y, b0.z, b0.w, b1.x, b1.y, b1.z, b1.w};
            #pragma unroll
            for (int i = 0; i < 8; i++)
                #pragma unroll
                for (int j = 0; j < 8; j++) acc[i][j] += a[i] * bb[j];
        }
        __syncthreads();
    }
    int nbase = nb * 128 + cg * 8;
    #pragma unroll
    for (int i = 0; i < 8; i++) {
        int o = rg * 8 + i;
        float inv  = bnw[o] * rsqrtf(bnv[o] + EPS);
        float bias = bnb[o] - bnm[o] * inv;
        float val[8];
        #pragma unroll
        for (int j = 0; j < 8; j++) val[j] = acc[i][j] * inv + bias;
        if (o < QKD) {
            #pragma unroll
            for (int j = 0; j < 8; j++)
                Qt[((size_t)b * N + nbase + j) * QKD + o] = (short)f2bf(val[j]);
        } else if (o < 2 * QKD) {
            #pragma unroll
            for (int j = 0; j < 8; j++)
                Kt[((size_t)b * N + nbase + j) * QKD + (o - QKD)] = (short)f2bf(val[j]);
        } else {
            short* vp = Vw + ((size_t)b * PD + (o - 2 * QKD)) * N + nbase;
            #pragma unroll
            for (int j = 0; j < 8; j += 2)
                *(unsigned*)(vp + j) = pack2(val[j], val[j + 1]);
        }
    }
}

// ---------------------------------------- K3: MFMA flash attention
// grid (B, 8): 4 waves/block, each wave owns 32 queries; full 1024-key loop.
// Writes silu(out) transposed bf16 into y1t[b][n][96].
__global__ __launch_bounds__(256) void k_attn(const short* __restrict__ Qt,
                                              const short* __restrict__ Kt,
                                              const short* __restrict__ Vb,
                                              short* __restrict__ y1t) {
    int b = blockIdx.x;
    int w = threadIdx.x >> 6, lane = threadIdx.x & 63;
    int col = lane & 31, hi = lane >> 5;
    int q0 = blockIdx.y * 128 + w * 32;

    const bf16x8 qf = *(const bf16x8*)(Qt + ((size_t)b * N + q0 + col) * QKD + hi * 8);
    f32x16 acc0 = zero16(), acc1 = zero16(), acc2 = zero16();
    float m = -1e30f, lsum = 0.f;
    const short* kbase = Kt + (size_t)b * N * QKD;
    const short* vbase = Vb + (size_t)b * PD * N;

    for (int m0 = 0; m0 < N; m0 += 32) {
        bf16x8 kf = *(const bf16x8*)(kbase + (size_t)(m0 + col) * QKD + hi * 8);
        f32x16 s = MFMA(kf, qf, zero16());   // s[r] = S[key=m0+crow(r,hi)][q]
        float cm = -1e30f;
        #pragma unroll
        for (int r = 0; r < 16; r++) { s[r] *= 0.25f; cm = fmaxf(cm, s[r]); }
        cm = fmaxf(cm, __shfl_xor(cm, 32, 64));
        float mnew = fmaxf(m, cm);
        float corr = __expf(m - mnew);
        m = mnew;
        lsum *= corr;
        #pragma unroll
        for (int r = 0; r < 16; r++) { acc0[r] *= corr; acc1[r] *= corr; acc2[r] *= corr; }
        float ps = 0.f;
        unsigned pw[8];
        #pragma unroll
        for (int j = 0; j < 8; j++) {
            float p0 = __expf(s[2 * j] - m), p1 = __expf(s[2 * j + 1] - m);
            ps += p0 + p1;
            pw[j] = pack2(p0, p1);
        }
        ps += __shfl_xor(ps, 32, 64);
        lsum += ps;
        unsigned xw[8];
        #pragma unroll
        for (int j = 0; j < 8; j++) xw[j] = __shfl_xor(pw[j], 32, 64);
        // Assemble B-fragments: P[k][q] with k = ks*16 + hi*8 + j (contiguous-8 layout)
        union { unsigned u[4]; bf16x8 v; } pb0, pb1;
        if (hi == 0) {
            pb0.u[0] = pw[0]; pb0.u[1] = pw[1]; pb0.u[2] = xw[0]; pb0.u[3] = xw[1];
            pb1.u[0] = pw[4]; pb1.u[1] = pw[5]; pb1.u[2] = xw[4]; pb1.u[3] = xw[5];
        } else {
            pb0.u[0] = xw[2]; pb0.u[1] = xw[3]; pb0.u[2] = pw[2]; pb0.u[3] = pw[3];
            pb1.u[0] = xw[6]; pb1.u[1] = xw[7]; pb1.u[2] = pw[6]; pb1.u[3] = pw[7];
        }
        const short* vrow = vbase + (size_t)col * N + m0 + hi * 8;
        bf16x8 v00 = *(const bf16x8*)(vrow);
        bf16x8 v01 = *(const bf16x8*)(vrow + 16);
        acc0 = MFMA(v00, pb0.v, acc0);
        acc0 = MFMA(v01, pb1.v, acc0);
        const short* vrow1 = vrow + 32 * N;
        bf16x8 v10 = *(const bf16x8*)(vrow1);
        bf16x8 v11 = *(const bf16x8*)(vrow1 + 16);
        acc1 = MFMA(v10, pb0.v, acc1);
        acc1 = MFMA(v11, pb1.v, acc1);
        const short* vrow2 = vrow1 + 32 * N;
        bf16x8 v20 = *(const bf16x8*)(vrow2);
        bf16x8 v21 = *(const bf16x8*)(vrow2 + 16);
        acc2 = MFMA(v20, pb0.v, acc2);
        acc2 = MFMA(v21, pb1.v, acc2);
    }
    float inv = 1.f / lsum;
    short* yrow = y1t + ((size_t)b * N + q0 + col) * PD;
    #pragma unroll
    for (int cg = 0; cg < 3; cg++) {
        f32x16 a = (cg == 0) ? acc0 : ((cg == 1) ? acc1 : acc2);
        #pragma unroll
        for (int j = 0; j < 8; j++) {
            float v0 = a[2 * j] * inv, v1 = a[2 * j + 1] * inv;
            v0 = v0 / (1.f + __expf(-v0));   // silu
            v1 = v1 / (1.f + __expf(-v1));
            int c = cg * 32 + ((2 * j) & 3) + 8 * (j >> 1) + 4 * hi;
            *(unsigned*)(yrow + c) = pack2(v0, v1);
        }
    }
}

// ---------------- K4: y2t[b][n][c-96] = bf16(silu(x[b][c][n])) for c in [96,384)
__global__ __launch_bounds__(256) void k_trans(const float* __restrict__ x,
                                               short* __restrict__ y2t) {
    int b = blockIdx.x, ct = blockIdx.y, nt = blockIdx.z;
    int tid = threadIdx.x;
    __shared__ short t[32][130];
    int c0 = PD + ct * 32, n0 = nt * 128;
    const float* xb = x + ((size_t)b * DIM + c0) * N + n0;
    #pragma unroll
    for (int i = 0; i < 16; i++) {
        int e = tid + 256 * i;
        int c = e >> 7, n = e & 127;
        float v = xb[(size_t)c * N + n];
        t[c][n] = (short)f2bf(v / (1.f + __expf(-v)));
    }
    __syncthreads();
    #pragma unroll
    for (int i = 0; i < 8; i++) {
        int e = tid + 256 * i;
        int n = e >> 4, cp = e & 15;
        unsigned lo = (unsigned short)t[2 * cp][n];
        unsigned hi = (unsigned short)t[2 * cp + 1][n];
        *(unsigned*)(y2t + ((size_t)b * N + n0 + n) * Y2C + ct * 32 + 2 * cp) = lo | (hi << 16);
    }
}

// ---------------- K5: W' = bf16(proj_w * bn_inv), bias[o]
__global__ __launch_bounds__(256) void k_wconv(const float* __restrict__ W,
                                               const float* __restrict__ bnw,
                                               const float* __restrict__ bnb,
                                               const float* __restrict__ bnm,
                                               const float* __restrict__ bnv,
                                               short* __restrict__ Wp,
                                               float* __restrict__ bias) {
    int idx = blockIdx.x * 256 + threadIdx.x;
    int o = idx / DIM;
    float inv = bnw[o] * rsqrtf(bnv[o] + EPS);
    Wp[idx] = (short)f2bf(W[idx] * inv);
    if (idx < DIM) bias[idx] = bnb[idx] - bnm[idx] * (bnw[idx] * rsqrtf(bnv[idx] + EPS));
}

// ---------------- K6: out = W' @ [y1t; y2t] + bias
// LDS-staged MFMA GEMM (m97 structure): 128o x 128n tile, BK=32, 4 waves,
// each wave a 64x64 quadrant as 2x2 of 32x32x16 frags.
// LDS XOR-swizzle (byte ^= (row&3)<<4) applied as: linear LDS dest +
// inverse-swizzled GLOBAL source + swizzled ds_read (rule #21).
__global__ __launch_bounds__(256) void k_proj(const short* __restrict__ Wp,
                                              const short* __restrict__ y1t,
                                              const short* __restrict__ y2t,
                                              const float* __restrict__ bias,
                                              float* __restrict__ out) {
    __shared__ short Asl[128 * 32];
    __shared__ short Bsl[128 * 32];
    int b = blockIdx.x, ob = blockIdx.y, nb = blockIdx.z;
    int tid = threadIdx.x, w = tid >> 6, l = tid & 63;
    int col = l & 31, hi = l >> 5;
    int wr = w >> 1, wc = w & 1;
    int o0 = ob * 128, n0 = nb * 128;
    size_t bn = (size_t)b * N + n0;

    f32x16 acc[2][2];
    acc[0][0] = zero16(); acc[0][1] = zero16();
    acc[1][0] = zero16(); acc[1][1] = zero16();

    int srow = (l >> 2);        // 0..15 within a 16-row issue
    int sslotbase = (l & 3);    // 16B slot within 64B row

    for (int step = 0; step < 12; step++) {
        int k0 = step * 32;
        const short* ysrc;
        int ystride, kq;
        if (k0 < PD) { ysrc = y1t; ystride = PD;  kq = k0; }
        else         { ysrc = y2t; ystride = Y2C; kq = k0 - PD; }
        // stage: wave w covers rows [w*32, w*32+32) of both A and B
        #pragma unroll
        for (int i = 0; i < 2; i++) {
            int row = w * 32 + i * 16 + srow;
            int sl = sslotbase ^ (row & 3);
            GLOAD16(Wp + (size_t)(o0 + row) * DIM + k0 + sl * 8,
                    &Asl[(w * 32 + i * 16) * 32]);
            GLOAD16(ysrc + (bn + row) * ystride + kq + sl * 8,
                    &Bsl[(w * 32 + i * 16) * 32]);
        }
        __syncthreads();
        #pragma unroll
        for (int kh = 0; kh < 2; kh++) {
            int bxor = ((kh << 5) + (hi << 4));
            int ra0 = wr * 64 + col,      ra1 = ra0 + 32;
            int rb0 = wc * 64 + col,      rb1 = rb0 + 32;
            bf16x8 a0 = *(const bf16x8*)&Asl[ra0 * 32 + ((bxor ^ ((ra0 & 3) << 4)) >> 1)];
            bf16x8 a1 = *(const bf16x8*)&Asl[ra1 * 32 + ((bxor ^ ((ra1 & 3) << 4)) >> 1)];
            bf16x8 b0 = *(const bf16x8*)&Bsl[rb0 * 32 + ((bxor ^ ((rb0 & 3) << 4)) >> 1)];
            bf16x8 b1 = *(const bf16x8*)&Bsl[rb1 * 32 + ((bxor ^ ((rb1 & 3) << 4)) >> 1)];
            acc[0][0] = MFMA(a0, b0, acc[0][0]);
            acc[0][1] = MFMA(a0, b1, acc[0][1]);
            acc[1][0] = MFMA(a1, b0, acc[1][0]);
            acc[1][1] = MFMA(a1, b1, acc[1][1]);
        }
        __syncthreads();
    }
    #pragma unroll
    for (int m = 0; m < 2; m++) {
        #pragma unroll
        for (int n = 0; n < 2; n++) {
            #pragma unroll
            for (int r = 0; r < 16; r++) {
                int o = o0 + wr * 64 + m * 32 + (r & 3) + 8 * (r >> 2) + 4 * hi;
                out[((size_t)b * DIM + o) * N + n0 + wc * 64 + n * 32 + col] =
                    acc[m][n][r] + bias[o];
            }
        }
    }
}

// -----------------------------------------------------------------------------
// ws layout (total ~50.6 MB): y2t aliases [Qt,Kt,Vw]+tail (dead after k_attn).
extern "C" void kernel_launch(void* const* d_in, const int* in_sizes, int n_in,
                              void* d_out, int out_size, void* d_ws, size_t ws_size,
                              hipStream_t stream) {
    const float* x    = (const float*)d_in[0];
    const float* gnw  = (const float*)d_in[1];
    const float* gnb  = (const float*)d_in[2];
    const float* qkvw = (const float*)d_in[3];
    const float* qbnw = (const float*)d_in[4];
    const float* qbnb = (const float*)d_in[5];
    const float* qbnm = (const float*)d_in[6];
    const float* qbnv = (const float*)d_in[7];
    const float* pw   = (const float*)d_in[8];
    const float* pbnw = (const float*)d_in[9];
    const float* pbnb = (const float*)d_in[10];
    const float* pbnm = (const float*)d_in[11];
    const float* pbnv = (const float*)d_in[12];
    float* out = (float*)d_out;

    char* p = (char*)d_ws;
    float* stats = (float*)p;  p += 1024;
    short* Wp    = (short*)p;  p += (size_t)DIM * DIM * 2;     // 288 KB
    float* bias  = (float*)p;  p += 1536;                      // DIM*4
    short* y1t   = (short*)p;  p += (size_t)B * N * PD * 2;    // 12.6 MB
    short* Qt    = (short*)p;                                  // 2 MB   (dead after k_attn)
    short* Kt    = Qt + (size_t)B * N * QKD;                   // 2 MB   (dead after k_attn)
    short* Vw    = Kt + (size_t)B * N * QKD;                   // 12.6 MB(dead after k_attn)
    short* y2t   = Qt;                                         // 37.75 MB alias

    k_gnstats<<<B, 256, 0, stream>>>(x, stats);
    k_wconv<<<DIM * DIM / 256, 256, 0, stream>>>(pw, pbnw, pbnb, pbnm, pbnv, Wp, bias);
    k_qkv<<<dim3(B, 8), 256, 0, stream>>>(x, stats, gnw, gnb, qkvw,
                                          qbnw, qbnb, qbnm, qbnv, Qt, Kt, Vw);
    k_attn<<<dim3(B, 8), 256, 0, stream>>>(Qt, Kt, Vw, y1t);
    k_trans<<<dim3(B, 9, 8), 256, 0, stream>>>(x, y2t);
    k_proj<<<dim3(B, 3, 8), 256, 0, stream>>>(Wp, y1t, y2t, bias, out);
}

// Round 5
// 159.830 us; speedup vs baseline: 4.8308x; 1.1759x over previous
//
#include <hip/hip_runtime.h>

#define EPS 1e-5f

constexpr int B   = 64;
constexpr int DIM = 384;
constexpr int PD  = 96;    // PDIM
constexpr int QKD = 16;    // QK
constexpr int N   = 1024;  // H*W
constexpr int OQ  = 128;   // 2*QK + PDIM
constexpr int Y2C = DIM - PD;  // 288

typedef __attribute__((ext_vector_type(8))) short bf16x8;
typedef __attribute__((ext_vector_type(16))) float f32x16;

#define MFMA(a, b, c) __builtin_amdgcn_mfma_f32_32x32x16_bf16((a), (b), (c), 0, 0, 0)

// async global->LDS, 16B per lane; LDS dest is wave-uniform base + lane*16
#define GLOAD16(gsrc, ldst)                                                    \
    __builtin_amdgcn_global_load_lds(                                          \
        (const __attribute__((address_space(1))) void*)(gsrc),                 \
        (__attribute__((address_space(3))) void*)(ldst), 16, 0, 0)

__device__ __forceinline__ unsigned short f2bf(float f) {
    union { float f; unsigned u; } v; v.f = f;
    unsigned r = v.u + 0x7fffu + ((v.u >> 16) & 1u);
    return (unsigned short)(r >> 16);
}
__device__ __forceinline__ unsigned pack2(float a, float b) {
    return (unsigned)f2bf(a) | ((unsigned)f2bf(b) << 16);
}
__device__ __forceinline__ f32x16 zero16() {
    f32x16 z;
#pragma unroll
    for (int i = 0; i < 16; i++) z[i] = 0.f;
    return z;
}

// ---------------------------------------------------------------- K1: GN stats
__global__ __launch_bounds__(256) void k_gnstats(const float* __restrict__ x,
                                                 float* __restrict__ stats) {
    int b = blockIdx.x;
    const float4* xp = (const float4*)(x + (size_t)b * DIM * N);
    float s1 = 0.f, s2 = 0.f;
    for (int i = threadIdx.x; i < PD * N / 4; i += 256) {
        float4 v = xp[i];
        s1 += v.x + v.y + v.z + v.w;
        s2 += v.x * v.x + v.y * v.y + v.z * v.z + v.w * v.w;
    }
    __shared__ float r1[4], r2[4];
    for (int o = 32; o > 0; o >>= 1) {
        s1 += __shfl_down(s1, o, 64);
        s2 += __shfl_down(s2, o, 64);
    }
    int wave = threadIdx.x >> 6, lane = threadIdx.x & 63;
    if (lane == 0) { r1[wave] = s1; r2[wave] = s2; }
    __syncthreads();
    if (threadIdx.x == 0) {
        float t1 = r1[0] + r1[1] + r1[2] + r1[3];
        float t2 = r2[0] + r2[1] + r2[2] + r2[3];
        float mu = t1 / (PD * N);
        float var = t2 / (PD * N) - mu * mu;
        stats[b * 2]     = mu;
        stats[b * 2 + 1] = rsqrtf(var + EPS);
    }
}

// ---------------- K2a: xgt[b][n][96] = bf16(GN(x1)) transposed
__global__ __launch_bounds__(256) void k_prep(const float* __restrict__ x,
                                              const float* __restrict__ stats,
                                              const float* __restrict__ gnw,
                                              const float* __restrict__ gnb,
                                              short* __restrict__ xgt) {
    int b = blockIdx.x, ct = blockIdx.y, nt = blockIdx.z;
    int tid = threadIdx.x;
    __shared__ short t[32][130];
    float mu = stats[2 * b], rsig = stats[2 * b + 1];
    int c0 = ct * 32, n0 = nt * 128;
    const float* xb = x + ((size_t)b * DIM + c0) * N + n0;
    #pragma unroll
    for (int i = 0; i < 16; i++) {
        int e = tid + 256 * i;
        int c = e >> 7, n = e & 127;
        float s = rsig * gnw[c0 + c];
        float tt = gnb[c0 + c] - mu * s;
        t[c][n] = (short)f2bf(s * xb[(size_t)c * N + n] + tt);
    }
    __syncthreads();
    #pragma unroll
    for (int i = 0; i < 8; i++) {
        int e = tid + 256 * i;
        int n = e >> 4, cp = e & 15;
        unsigned lo = (unsigned short)t[2 * cp][n];
        unsigned hi = (unsigned short)t[2 * cp + 1][n];
        *(unsigned*)(xgt + ((size_t)b * N + n0 + n) * PD + c0 + 2 * cp) = lo | (hi << 16);
    }
}

// ---------------- K2b: Wq = bf16(qkv_w * bn_inv), qbias
__global__ __launch_bounds__(256) void k_wconv2(const float* __restrict__ W,
                                                const float* __restrict__ bnw,
                                                const float* __restrict__ bnb,
                                                const float* __restrict__ bnm,
                                                const float* __restrict__ bnv,
                                                short* __restrict__ Wq,
                                                float* __restrict__ qbias) {
    int idx = blockIdx.x * 256 + threadIdx.x;
    int o = idx / PD;
    float inv = bnw[o] * rsqrtf(bnv[o] + EPS);
    Wq[idx] = (short)f2bf(W[idx] * inv);
    if (idx < OQ) qbias[idx] = bnb[idx] - bnm[idx] * (bnw[idx] * rsqrtf(bnv[idx] + EPS));
}

// ---------------- K2c: MFMA QKV GEMM: [128 o] x [128 n], K=96 single-shot.
// grid (B, 8). LDS [128][104] padded rows (<=4-way read conflicts).
__global__ __launch_bounds__(256) void k_qkv(const short* __restrict__ Wq,
                                             const short* __restrict__ xgt,
                                             const float* __restrict__ qbias,
                                             short* __restrict__ Qt,
                                             short* __restrict__ Kt,
                                             short* __restrict__ Vw) {
    alignas(16) __shared__ short Wl[128 * 104];
    alignas(16) __shared__ short Xl[128 * 104];
    __shared__ float qbl[OQ];
    int b = blockIdx.x, nb = blockIdx.y;
    int tid = threadIdx.x, w = tid >> 6, l = tid & 63;
    int col = l & 31, hi = l >> 5;
    int wr = w >> 1, wc = w & 1;
    int n0 = nb * 128;
    const short* xg = xgt + ((size_t)b * N + n0) * PD;

    if (tid < OQ) qbl[tid] = qbias[tid];
    #pragma unroll
    for (int it = 0; it < 6; it++) {
        int e = tid + 256 * it;          // 0..1535
        int row = e / 12, slot = e % 12;
        uint4 wa = *(const uint4*)(Wq + row * PD + slot * 8);
        uint4 xa = *(const uint4*)(xg + (size_t)row * PD + slot * 8);
        *(uint4*)&Wl[row * 104 + slot * 8] = wa;
        *(uint4*)&Xl[row * 104 + slot * 8] = xa;
    }
    __syncthreads();

    f32x16 acc[2][2];
    acc[0][0] = zero16(); acc[0][1] = zero16();
    acc[1][0] = zero16(); acc[1][1] = zero16();
    #pragma unroll
    for (int ks = 0; ks < 6; ks++) {
        int ko = ks * 16 + hi * 8;
        int ra0 = wr * 64 + col, ra1 = ra0 + 32;
        int rb0 = wc * 64 + col, rb1 = rb0 + 32;
        bf16x8 a0 = *(const bf16x8*)&Wl[ra0 * 104 + ko];
        bf16x8 a1 = *(const bf16x8*)&Wl[ra1 * 104 + ko];
        bf16x8 b0 = *(const bf16x8*)&Xl[rb0 * 104 + ko];
        bf16x8 b1 = *(const bf16x8*)&Xl[rb1 * 104 + ko];
        acc[0][0] = MFMA(a0, b0, acc[0][0]);
        acc[0][1] = MFMA(a0, b1, acc[0][1]);
        acc[1][0] = MFMA(a1, b0, acc[1][0]);
        acc[1][1] = MFMA(a1, b1, acc[1][1]);
    }

    #pragma unroll
    for (int m = 0; m < 2; m++) {
        int o_base = wr * 64 + m * 32;
        #pragma unroll
        for (int nn = 0; nn < 2; nn++) {
            int n = n0 + wc * 64 + nn * 32 + col;
            f32x16 a = acc[m][nn];
            if (o_base == 0) {
                // o 0..15 -> Q, 16..31 -> K
                #pragma unroll
                for (int g = 0; g < 4; g++) {
                    int ofr = 8 * g + 4 * hi;   // frag-o base: 0,8,16,24 (+4hi)
                    float v0 = a[4 * g + 0] + qbl[ofr + 0];
                    float v1 = a[4 * g + 1] + qbl[ofr + 1];
                    float v2 = a[4 * g + 2] + qbl[ofr + 2];
                    float v3 = a[4 * g + 3] + qbl[ofr + 3];
                    uint2 d; d.x = pack2(v0, v1); d.y = pack2(v2, v3);
                    short* dst = (g < 2)
                        ? (Qt + ((size_t)b * N + n) * QKD + (ofr & 15))
                        : (Kt + ((size_t)b * N + n) * QKD + (ofr & 15));
                    *(uint2*)dst = d;
                }
            } else {
                int c0 = o_base - 32;          // 0, 32, 64
                short* vb = Vw + ((size_t)b * PD + c0) * N + n;
                #pragma unroll
                for (int r = 0; r < 16; r++) {
                    int cf = (r & 3) + 8 * (r >> 2) + 4 * hi;
                    vb[(size_t)cf * N] = (short)f2bf(a[r] + qbl[32 + c0 + cf]);
                }
            }
        }
    }
}

// ---------------------------------------- K3: MFMA flash attention
// grid (B, 8): 4 waves/block, each wave owns 32 queries; full 1024-key loop.
// Writes silu(out) transposed bf16 into y1t[b][n][96].
__global__ __launch_bounds__(256) void k_attn(const short* __restrict__ Qt,
                                              const short* __restrict__ Kt,
                                              const short* __restrict__ Vb,
                                              short* __restrict__ y1t) {
    int b = blockIdx.x;
    int w = threadIdx.x >> 6, lane = threadIdx.x & 63;
    int col = lane & 31, hi = lane >> 5;
    int q0 = blockIdx.y * 128 + w * 32;

    const bf16x8 qf = *(const bf16x8*)(Qt + ((size_t)b * N + q0 + col) * QKD + hi * 8);
    f32x16 acc0 = zero16(), acc1 = zero16(), acc2 = zero16();
    float m = -1e30f, lsum = 0.f;
    const short* kbase = Kt + (size_t)b * N * QKD;
    const short* vbase = Vb + (size_t)b * PD * N;

    for (int m0 = 0; m0 < N; m0 += 32) {
        bf16x8 kf = *(const bf16x8*)(kbase + (size_t)(m0 + col) * QKD + hi * 8);
        f32x16 s = MFMA(kf, qf, zero16());   // s[r] = S[key=m0+crow(r,hi)][q]
        float cm = -1e30f;
        #pragma unroll
        for (int r = 0; r < 16; r++) { s[r] *= 0.25f; cm = fmaxf(cm, s[r]); }
        cm = fmaxf(cm, __shfl_xor(cm, 32, 64));
        float mnew = fmaxf(m, cm);
        float corr = __expf(m - mnew);
        m = mnew;
        lsum *= corr;
        #pragma unroll
        for (int r = 0; r < 16; r++) { acc0[r] *= corr; acc1[r] *= corr; acc2[r] *= corr; }
        float ps = 0.f;
        unsigned pw[8];
        #pragma unroll
        for (int j = 0; j < 8; j++) {
            float p0 = __expf(s[2 * j] - m), p1 = __expf(s[2 * j + 1] - m);
            ps += p0 + p1;
            pw[j] = pack2(p0, p1);
        }
        ps += __shfl_xor(ps, 32, 64);
        lsum += ps;
        unsigned xw[8];
        #pragma unroll
        for (int j = 0; j < 8; j++) xw[j] = __shfl_xor(pw[j], 32, 64);
        // Assemble B-fragments: P[k][q] with k = ks*16 + hi*8 + j (contiguous-8 layout)
        union { unsigned u[4]; bf16x8 v; } pb0, pb1;
        if (hi == 0) {
            pb0.u[0] = pw[0]; pb0.u[1] = pw[1]; pb0.u[2] = xw[0]; pb0.u[3] = xw[1];
            pb1.u[0] = pw[4]; pb1.u[1] = pw[5]; pb1.u[2] = xw[4]; pb1.u[3] = xw[5];
        } else {
            pb0.u[0] = xw[2]; pb0.u[1] = xw[3]; pb0.u[2] = pw[2]; pb0.u[3] = pw[3];
            pb1.u[0] = xw[6]; pb1.u[1] = xw[7]; pb1.u[2] = pw[6]; pb1.u[3] = pw[7];
        }
        const short* vrow = vbase + (size_t)col * N + m0 + hi * 8;
        bf16x8 v00 = *(const bf16x8*)(vrow);
        bf16x8 v01 = *(const bf16x8*)(vrow + 16);
        acc0 = MFMA(v00, pb0.v, acc0);
        acc0 = MFMA(v01, pb1.v, acc0);
        const short* vrow1 = vrow + 32 * N;
        bf16x8 v10 = *(const bf16x8*)(vrow1);
        bf16x8 v11 = *(const bf16x8*)(vrow1 + 16);
        acc1 = MFMA(v10, pb0.v, acc1);
        acc1 = MFMA(v11, pb1.v, acc1);
        const short* vrow2 = vrow1 + 32 * N;
        bf16x8 v20 = *(const bf16x8*)(vrow2);
        bf16x8 v21 = *(const bf16x8*)(vrow2 + 16);
        acc2 = MFMA(v20, pb0.v, acc2);
        acc2 = MFMA(v21, pb1.v, acc2);
    }
    float inv = 1.f / lsum;
    short* yrow = y1t + ((size_t)b * N + q0 + col) * PD;
    #pragma unroll
    for (int cg = 0; cg < 3; cg++) {
        f32x16 a = (cg == 0) ? acc0 : ((cg == 1) ? acc1 : acc2);
        #pragma unroll
        for (int j = 0; j < 8; j++) {
            float v0 = a[2 * j] * inv, v1 = a[2 * j + 1] * inv;
            v0 = v0 / (1.f + __expf(-v0));   // silu
            v1 = v1 / (1.f + __expf(-v1));
            int c = cg * 32 + ((2 * j) & 3) + 8 * (j >> 1) + 4 * hi;
            *(unsigned*)(yrow + c) = pack2(v0, v1);
        }
    }
}

// ---------------- K4: y2t[b][n][c-96] = bf16(silu(x[b][c][n])) for c in [96,384)
__global__ __launch_bounds__(256) void k_trans(const float* __restrict__ x,
                                               short* __restrict__ y2t) {
    int b = blockIdx.x, ct = blockIdx.y, nt = blockIdx.z;
    int tid = threadIdx.x;
    __shared__ short t[32][130];
    int c0 = PD + ct * 32, n0 = nt * 128;
    const float* xb = x + ((size_t)b * DIM + c0) * N + n0;
    #pragma unroll
    for (int i = 0; i < 16; i++) {
        int e = tid + 256 * i;
        int c = e >> 7, n = e & 127;
        float v = xb[(size_t)c * N + n];
        t[c][n] = (short)f2bf(v / (1.f + __expf(-v)));
    }
    __syncthreads();
    #pragma unroll
    for (int i = 0; i < 8; i++) {
        int e = tid + 256 * i;
        int n = e >> 4, cp = e & 15;
        unsigned lo = (unsigned short)t[2 * cp][n];
        unsigned hi = (unsigned short)t[2 * cp + 1][n];
        *(unsigned*)(y2t + ((size_t)b * N + n0 + n) * Y2C + ct * 32 + 2 * cp) = lo | (hi << 16);
    }
}

// ---------------- K5: W' = bf16(proj_w * bn_inv), bias[o]
__global__ __launch_bounds__(256) void k_wconv(const float* __restrict__ W,
                                               const float* __restrict__ bnw,
                                               const float* __restrict__ bnb,
                                               const float* __restrict__ bnm,
                                               const float* __restrict__ bnv,
                                               short* __restrict__ Wp,
                                               float* __restrict__ bias) {
    int idx = blockIdx.x * 256 + threadIdx.x;
    int o = idx / DIM;
    float inv = bnw[o] * rsqrtf(bnv[o] + EPS);
    Wp[idx] = (short)f2bf(W[idx] * inv);
    if (idx < DIM) bias[idx] = bnb[idx] - bnm[idx] * (bnw[idx] * rsqrtf(bnv[idx] + EPS));
}

// ---------------- K6: out = W' @ [y1t; y2t] + bias
// LDS-staged MFMA GEMM (m97 structure): 128o x 128n tile, BK=32, 4 waves,
// each wave a 64x64 quadrant as 2x2 of 32x32x16 frags.
__global__ __launch_bounds__(256) void k_proj(const short* __restrict__ Wp,
                                              const short* __restrict__ y1t,
                                              const short* __restrict__ y2t,
                                              const float* __restrict__ bias,
                                              float* __restrict__ out) {
    __shared__ short Asl[128 * 32];
    __shared__ short Bsl[128 * 32];
    int b = blockIdx.x, ob = blockIdx.y, nb = blockIdx.z;
    int tid = threadIdx.x, w = tid >> 6, l = tid & 63;
    int col = l & 31, hi = l >> 5;
    int wr = w >> 1, wc = w & 1;
    int o0 = ob * 128, n0 = nb * 128;
    size_t bn = (size_t)b * N + n0;

    f32x16 acc[2][2];
    acc[0][0] = zero16(); acc[0][1] = zero16();
    acc[1][0] = zero16(); acc[1][1] = zero16();

    int srow = (l >> 2);        // 0..15 within a 16-row issue
    int sslotbase = (l & 3);    // 16B slot within 64B row

    for (int step = 0; step < 12; step++) {
        int k0 = step * 32;
        const short* ysrc;
        int ystride, kq;
        if (k0 < PD) { ysrc = y1t; ystride = PD;  kq = k0; }
        else         { ysrc = y2t; ystride = Y2C; kq = k0 - PD; }
        #pragma unroll
        for (int i = 0; i < 2; i++) {
            int row = w * 32 + i * 16 + srow;
            int sl = sslotbase ^ (row & 3);
            GLOAD16(Wp + (size_t)(o0 + row) * DIM + k0 + sl * 8,
                    &Asl[(w * 32 + i * 16) * 32]);
            GLOAD16(ysrc + (bn + row) * ystride + kq + sl * 8,
                    &Bsl[(w * 32 + i * 16) * 32]);
        }
        __syncthreads();
        #pragma unroll
        for (int kh = 0; kh < 2; kh++) {
            int bxor = ((kh << 5) + (hi << 4));
            int ra0 = wr * 64 + col,      ra1 = ra0 + 32;
            int rb0 = wc * 64 + col,      rb1 = rb0 + 32;
            bf16x8 a0 = *(const bf16x8*)&Asl[ra0 * 32 + ((bxor ^ ((ra0 & 3) << 4)) >> 1)];
            bf16x8 a1 = *(const bf16x8*)&Asl[ra1 * 32 + ((bxor ^ ((ra1 & 3) << 4)) >> 1)];
            bf16x8 b0 = *(const bf16x8*)&Bsl[rb0 * 32 + ((bxor ^ ((rb0 & 3) << 4)) >> 1)];
            bf16x8 b1 = *(const bf16x8*)&Bsl[rb1 * 32 + ((bxor ^ ((rb1 & 3) << 4)) >> 1)];
            acc[0][0] = MFMA(a0, b0, acc[0][0]);
            acc[0][1] = MFMA(a0, b1, acc[0][1]);
            acc[1][0] = MFMA(a1, b0, acc[1][0]);
            acc[1][1] = MFMA(a1, b1, acc[1][1]);
        }
        __syncthreads();
    }
    #pragma unroll
    for (int m = 0; m < 2; m++) {
        #pragma unroll
        for (int n = 0; n < 2; n++) {
            #pragma unroll
            for (int r = 0; r < 16; r++) {
                int o = o0 + wr * 64 + m * 32 + (r & 3) + 8 * (r >> 2) + 4 * hi;
                out[((size_t)b * DIM + o) * N + n0 + wc * 64 + n * 32 + col] =
                    acc[m][n][r] + bias[o];
            }
        }
    }
}

// -----------------------------------------------------------------------------
// ws layout (~50.7 MB): y2t aliases [xgt,Qt,Kt,Vw]+tail — xgt dead after k_qkv,
// Qt/Kt/Vw dead after k_attn; k_trans runs after k_attn on the same stream.
extern "C" void kernel_launch(void* const* d_in, const int* in_sizes, int n_in,
                              void* d_out, int out_size, void* d_ws, size_t ws_size,
                              hipStream_t stream) {
    const float* x    = (const float*)d_in[0];
    const float* gnw  = (const float*)d_in[1];
    const float* gnb  = (const float*)d_in[2];
    const float* qkvw = (const float*)d_in[3];
    const float* qbnw = (const float*)d_in[4];
    const float* qbnb = (const float*)d_in[5];
    const float* qbnm = (const float*)d_in[6];
    const float* qbnv = (const float*)d_in[7];
    const float* pw   = (const float*)d_in[8];
    const float* pbnw = (const float*)d_in[9];
    const float* pbnb = (const float*)d_in[10];
    const float* pbnm = (const float*)d_in[11];
    const float* pbnv = (const float*)d_in[12];
    float* out = (float*)d_out;

    char* p = (char*)d_ws;
    float* stats = (float*)p;  p += 1024;
    short* Wp    = (short*)p;  p += (size_t)DIM * DIM * 2;     // 288 KB
    float* bias  = (float*)p;  p += 1536;                      // DIM*4
    short* Wq    = (short*)p;  p += (size_t)OQ * PD * 2;       // 24 KB
    float* qbias = (float*)p;  p += 512;                       // OQ*4
    short* y1t   = (short*)p;  p += (size_t)B * N * PD * 2;    // 12.6 MB
    short* xgt   = (short*)p;                                  // 12.6 MB (dead after k_qkv)
    short* Qt    = xgt + (size_t)B * N * PD;                   // 2 MB    (dead after k_attn)
    short* Kt    = Qt + (size_t)B * N * QKD;                   // 2 MB    (dead after k_attn)
    short* Vw    = Kt + (size_t)B * N * QKD;                   // 12.6 MB (dead after k_attn)
    short* y2t   = xgt;                                        // 37.75 MB alias

    k_gnstats<<<B, 256, 0, stream>>>(x, stats);
    k_wconv<<<DIM * DIM / 256, 256, 0, stream>>>(pw, pbnw, pbnb, pbnm, pbnv, Wp, bias);
    k_wconv2<<<OQ * PD / 256, 256, 0, stream>>>(qkvw, qbnw, qbnb, qbnm, qbnv, Wq, qbias);
    k_prep<<<dim3(B, 3, 8), 256, 0, stream>>>(x, stats, gnw, gnb, xgt);
    k_qkv<<<dim3(B, 8), 256, 0, stream>>>(Wq, xgt, qbias, Qt, Kt, Vw);
    k_attn<<<dim3(B, 8), 256, 0, stream>>>(Qt, Kt, Vw, y1t);
    k_trans<<<dim3(B, 9, 8), 256, 0, stream>>>(x, y2t);
    k_proj<<<dim3(B, 3, 8), 256, 0, stream>>>(Wp, y1t, y2t, bias, out);
}